// Round 1
// baseline (42.551 us; speedup 1.0000x reference)
//
#include <hip/hip_runtime.h>

#define KLD_EPS 1e-6f

// Stage 1: per-block partial sums of KL over rows.
// 8 lanes cooperate per row b: lane sub in [0,8) loads float4 (x0,y0,x1,y1)
// = true[b, 2*sub:2*sub+2, :]. Wave reads contiguous 1 KiB per iteration.
__global__ __launch_bounds__(256) void gaze_kld_partial(
    const float* __restrict__ pred,
    const float* __restrict__ tru,
    float* __restrict__ partial,
    int B)
{
    const int t   = threadIdx.x;
    const int sub = t & 7;
    const int groupsPerBlock = blockDim.x >> 3;               // 32
    const int strideG = gridDim.x * groupsPerBlock;

    const float4* __restrict__ tru4  = (const float4*)tru;    // 8 float4 per row
    const float4* __restrict__ pred4 = (const float4*)pred;   // 1 float4 per row

    float local = 0.0f;

    for (int b = blockIdx.x * groupsPerBlock + (t >> 3); b < B; b += strideG) {
        float4 v = tru4[b * 8 + sub];
        float sx  = v.x + v.z;
        float sy  = v.y + v.w;
        float sxx = v.x * v.x + v.z * v.z;
        float syy = v.y * v.y + v.w * v.w;

        // reduce within the 8-lane group (xor masks stay inside the group)
        #pragma unroll
        for (int m = 1; m < 8; m <<= 1) {
            sx  += __shfl_xor(sx,  m);
            sy  += __shfl_xor(sy,  m);
            sxx += __shfl_xor(sxx, m);
            syy += __shfl_xor(syy, m);
        }

        if (sub == 0) {
            float4 p  = pred4[b];
            float pmx = p.x, pmy = p.y;
            float pvx = p.z + KLD_EPS, pvy = p.w + KLD_EPS;

            float tmx = sx * (1.0f / 16.0f);
            float tmy = sy * (1.0f / 16.0f);
            // unbiased variance: (sum x^2 - 16*mean^2) / 15
            float tvx = (sxx - 16.0f * tmx * tmx) * (1.0f / 15.0f) + KLD_EPS;
            float tvy = (syy - 16.0f * tmy * tmy) * (1.0f / 15.0f) + KLD_EPS;

            float dx = pmx - tmx, dy = pmy - tmy;
            float kl = 0.5f * ( logf(pvx / tvx) + tvx / pvx + dx * dx / pvx
                              + logf(pvy / tvy) + tvy / pvy + dy * dy / pvy
                              - 2.0f );
            local += kl;
        }
    }

    // deterministic block reduction: full-wave shuffle then LDS across 4 waves
    __shared__ float sm[4];
    #pragma unroll
    for (int off = 32; off > 0; off >>= 1)
        local += __shfl_down(local, off);
    if ((t & 63) == 0) sm[t >> 6] = local;
    __syncthreads();
    if (t == 0)
        partial[blockIdx.x] = (sm[0] + sm[1]) + (sm[2] + sm[3]);
}

// Stage 2: single block sums the per-block partials (fixed order) and scales.
__global__ __launch_bounds__(256) void gaze_kld_final(
    const float* __restrict__ partial, int n,
    float* __restrict__ out, float invB)
{
    const int t = threadIdx.x;
    float s = 0.0f;
    for (int i = t; i < n; i += blockDim.x) s += partial[i];

    __shared__ float sm[4];
    #pragma unroll
    for (int off = 32; off > 0; off >>= 1)
        s += __shfl_down(s, off);
    if ((t & 63) == 0) sm[t >> 6] = s;
    __syncthreads();
    if (t == 0)
        out[0] = ((sm[0] + sm[1]) + (sm[2] + sm[3])) * invB;
}

extern "C" void kernel_launch(void* const* d_in, const int* in_sizes, int n_in,
                              void* d_out, int out_size, void* d_ws, size_t ws_size,
                              hipStream_t stream) {
    const float* pred = (const float*)d_in[0];
    const float* tru  = (const float*)d_in[1];
    float* out = (float*)d_out;

    const int B = in_sizes[0] / 4;   // pred is (B,4)

    int blocks = 2048;
    // safety: one float partial per block must fit in workspace
    size_t maxBlocks = ws_size / sizeof(float);
    if ((size_t)blocks > maxBlocks) blocks = (int)maxBlocks;
    if (blocks < 1) blocks = 1;

    float* partials = (float*)d_ws;

    gaze_kld_partial<<<blocks, 256, 0, stream>>>(pred, tru, partials, B);
    gaze_kld_final<<<1, 256, 0, stream>>>(partials, blocks, out, 1.0f / (float)B);
}

// Round 2
// 32.850 us; speedup vs baseline: 1.2953x; 1.2953x over previous
//
#include <hip/hip_runtime.h>

#define KLD_EPS 1e-6f

// Stage 1: one thread owns one row b. Row = 8 float4 = 128 B = one cache line,
// so the wave's 8 loads cover a contiguous 8 KiB block with full line reuse.
// No shuffles, no divergence in the hot path.
__global__ __launch_bounds__(256) void gaze_kld_partial(
    const float* __restrict__ pred,
    const float* __restrict__ tru,
    float* __restrict__ partial,
    int B)
{
    const int t = threadIdx.x;
    const int gid = blockIdx.x * blockDim.x + t;
    const int stride = gridDim.x * blockDim.x;

    const float4* __restrict__ tru4  = (const float4*)tru;    // 8 float4 per row
    const float4* __restrict__ pred4 = (const float4*)pred;   // 1 float4 per row

    float local = 0.0f;

    for (int b = gid; b < B; b += stride) {
        // issue all 9 independent loads up front
        float4 v0 = tru4[b * 8 + 0];
        float4 v1 = tru4[b * 8 + 1];
        float4 v2 = tru4[b * 8 + 2];
        float4 v3 = tru4[b * 8 + 3];
        float4 v4 = tru4[b * 8 + 4];
        float4 v5 = tru4[b * 8 + 5];
        float4 v6 = tru4[b * 8 + 6];
        float4 v7 = tru4[b * 8 + 7];
        float4 p  = pred4[b];

        float sx  = (v0.x + v1.x) + (v2.x + v3.x) + (v4.x + v5.x) + (v6.x + v7.x)
                  + (v0.z + v1.z) + (v2.z + v3.z) + (v4.z + v5.z) + (v6.z + v7.z);
        float sy  = (v0.y + v1.y) + (v2.y + v3.y) + (v4.y + v5.y) + (v6.y + v7.y)
                  + (v0.w + v1.w) + (v2.w + v3.w) + (v4.w + v5.w) + (v6.w + v7.w);
        float sxx = v0.x*v0.x + v1.x*v1.x + v2.x*v2.x + v3.x*v3.x
                  + v4.x*v4.x + v5.x*v5.x + v6.x*v6.x + v7.x*v7.x
                  + v0.z*v0.z + v1.z*v1.z + v2.z*v2.z + v3.z*v3.z
                  + v4.z*v4.z + v5.z*v5.z + v6.z*v6.z + v7.z*v7.z;
        float syy = v0.y*v0.y + v1.y*v1.y + v2.y*v2.y + v3.y*v3.y
                  + v4.y*v4.y + v5.y*v5.y + v6.y*v6.y + v7.y*v7.y
                  + v0.w*v0.w + v1.w*v1.w + v2.w*v2.w + v3.w*v3.w
                  + v4.w*v4.w + v5.w*v5.w + v6.w*v6.w + v7.w*v7.w;

        float pmx = p.x, pmy = p.y;
        float pvx = p.z + KLD_EPS, pvy = p.w + KLD_EPS;

        float tmx = sx * (1.0f / 16.0f);
        float tmy = sy * (1.0f / 16.0f);
        // unbiased variance: (sum x^2 - 16*mean^2) / 15
        float tvx = (sxx - 16.0f * tmx * tmx) * (1.0f / 15.0f) + KLD_EPS;
        float tvy = (syy - 16.0f * tmy * tmy) * (1.0f / 15.0f) + KLD_EPS;

        float dx = pmx - tmx, dy = pmy - tmy;
        local += 0.5f * ( logf(pvx / tvx) + tvx / pvx + dx * dx / pvx
                        + logf(pvy / tvy) + tvy / pvy + dy * dy / pvy
                        - 2.0f );
    }

    // deterministic block reduction: full-wave shuffle then LDS across 4 waves
    __shared__ float sm[4];
    #pragma unroll
    for (int off = 32; off > 0; off >>= 1)
        local += __shfl_down(local, off);
    if ((t & 63) == 0) sm[t >> 6] = local;
    __syncthreads();
    if (t == 0)
        partial[blockIdx.x] = (sm[0] + sm[1]) + (sm[2] + sm[3]);
}

// Stage 2: single block sums the per-block partials (fixed order) and scales.
__global__ __launch_bounds__(256) void gaze_kld_final(
    const float* __restrict__ partial, int n,
    float* __restrict__ out, float invB)
{
    const int t = threadIdx.x;
    float s = 0.0f;
    for (int i = t; i < n; i += blockDim.x) s += partial[i];

    __shared__ float sm[4];
    #pragma unroll
    for (int off = 32; off > 0; off >>= 1)
        s += __shfl_down(s, off);
    if ((t & 63) == 0) sm[t >> 6] = s;
    __syncthreads();
    if (t == 0)
        out[0] = ((sm[0] + sm[1]) + (sm[2] + sm[3])) * invB;
}

extern "C" void kernel_launch(void* const* d_in, const int* in_sizes, int n_in,
                              void* d_out, int out_size, void* d_ws, size_t ws_size,
                              hipStream_t stream) {
    const float* pred = (const float*)d_in[0];
    const float* tru  = (const float*)d_in[1];
    float* out = (float*)d_out;

    const int B = in_sizes[0] / 4;   // pred is (B,4)

    // one thread per row
    int blocks = (B + 255) / 256;
    size_t maxBlocks = ws_size / sizeof(float);
    if ((size_t)blocks > maxBlocks) blocks = (int)maxBlocks;
    if (blocks < 1) blocks = 1;

    float* partials = (float*)d_ws;

    gaze_kld_partial<<<blocks, 256, 0, stream>>>(pred, tru, partials, B);
    gaze_kld_final<<<1, 256, 0, stream>>>(partials, blocks, out, 1.0f / (float)B);
}

// Round 3
// 30.685 us; speedup vs baseline: 1.3867x; 1.0705x over previous
//
#include <hip/hip_runtime.h>

#define KLD_EPS 1e-6f

// Stage 1: coalesced global -> XOR-swizzled LDS -> per-thread row compute.
// Tile = 256 rows x 8 float4 (32 KiB). Element (r,k) stored at
// lds4[r*8 + (k ^ (r&7))]; writes from linear loads stay conflict-free,
// per-row reads use offset k ^ (t&7) to hit all 8 bank-groups.
// Row sums are permutation-invariant, so no un-swizzle is needed.
__global__ __launch_bounds__(256) void gaze_kld_partial(
    const float* __restrict__ pred,
    const float* __restrict__ tru,
    float* __restrict__ partial,
    int B, int nTiles)
{
    __shared__ float4 lds4[2048];   // 32 KiB

    const int t = threadIdx.x;
    const float4* __restrict__ tru4  = (const float4*)tru;   // 8 float4 per row
    const float4* __restrict__ pred4 = (const float4*)pred;  // 1 float4 per row

    float local = 0.0f;
    const long long totF4 = (long long)B * 8;

    for (int tb = blockIdx.x; tb < nTiles; tb += gridDim.x) {
        const long long gBase = (long long)tb * 2048;

        // ---- coalesced global -> swizzled LDS ----
        #pragma unroll
        for (int i = 0; i < 8; ++i) {
            int gl = i * 256 + t;            // local float4 idx within tile
            long long g = gBase + gl;
            float4 v = make_float4(0.f, 0.f, 0.f, 0.f);
            if (g < totF4) v = tru4[g];
            int r = gl >> 3;                 // local row
            int k = gl & 7;
            lds4[r * 8 + (k ^ (r & 7))] = v;
        }

        // pred for own row (independent, issued alongside)
        const int row = tb * 256 + t;
        float4 p = make_float4(0.f, 0.f, 1.f, 1.f);
        if (row < B) p = pred4[row];

        __syncthreads();

        // ---- per-thread row read from LDS ----
        float sx = 0.f, sy = 0.f, sxx = 0.f, syy = 0.f;
        #pragma unroll
        for (int k = 0; k < 8; ++k) {
            float4 v = lds4[t * 8 + (k ^ (t & 7))];
            sx  += v.x + v.z;
            sy  += v.y + v.w;
            sxx += v.x * v.x + v.z * v.z;
            syy += v.y * v.y + v.w * v.w;
        }

        __syncthreads();   // reads done before next iteration's writes

        if (row < B) {
            float pmx = p.x, pmy = p.y;
            float pvx = p.z + KLD_EPS, pvy = p.w + KLD_EPS;

            float tmx = sx * (1.0f / 16.0f);
            float tmy = sy * (1.0f / 16.0f);
            float tvx = (sxx - 16.0f * tmx * tmx) * (1.0f / 15.0f) + KLD_EPS;
            float tvy = (syy - 16.0f * tmy * tmy) * (1.0f / 15.0f) + KLD_EPS;

            float dx = pmx - tmx, dy = pmy - tmy;
            local += 0.5f * ( __logf(pvx / tvx) + tvx / pvx + dx * dx / pvx
                            + __logf(pvy / tvy) + tvy / pvy + dy * dy / pvy
                            - 2.0f );
        }
    }

    // deterministic block reduction
    __shared__ float sm[4];
    #pragma unroll
    for (int off = 32; off > 0; off >>= 1)
        local += __shfl_down(local, off);
    if ((t & 63) == 0) sm[t >> 6] = local;
    __syncthreads();
    if (t == 0)
        partial[blockIdx.x] = (sm[0] + sm[1]) + (sm[2] + sm[3]);
}

// Stage 2: single block sums per-block partials in fixed order, scales by 1/B.
__global__ __launch_bounds__(256) void gaze_kld_final(
    const float* __restrict__ partial, int n,
    float* __restrict__ out, float invB)
{
    const int t = threadIdx.x;
    float s = 0.0f;
    for (int i = t; i < n; i += blockDim.x) s += partial[i];

    __shared__ float sm[4];
    #pragma unroll
    for (int off = 32; off > 0; off >>= 1)
        s += __shfl_down(s, off);
    if ((t & 63) == 0) sm[t >> 6] = s;
    __syncthreads();
    if (t == 0)
        out[0] = ((sm[0] + sm[1]) + (sm[2] + sm[3])) * invB;
}

extern "C" void kernel_launch(void* const* d_in, const int* in_sizes, int n_in,
                              void* d_out, int out_size, void* d_ws, size_t ws_size,
                              hipStream_t stream) {
    const float* pred = (const float*)d_in[0];
    const float* tru  = (const float*)d_in[1];
    float* out = (float*)d_out;

    const int B = in_sizes[0] / 4;         // pred is (B,4)
    const int nTiles = (B + 255) / 256;

    int blocks = 1024;                     // 4 blocks/CU co-resident (32 KiB LDS each)
    if (blocks > nTiles) blocks = nTiles;
    size_t maxBlocks = ws_size / sizeof(float);
    if ((size_t)blocks > maxBlocks) blocks = (int)maxBlocks;
    if (blocks < 1) blocks = 1;

    float* partials = (float*)d_ws;

    gaze_kld_partial<<<blocks, 256, 0, stream>>>(pred, tru, partials, B, nTiles);
    gaze_kld_final<<<1, 256, 0, stream>>>(partials, blocks, out, 1.0f / (float)B);
}